// Round 1
// baseline (1688.878 us; speedup 1.0000x reference)
//
#include <hip/hip_runtime.h>

// ---------------------------------------------------------------------------
// GNNDecoder: h = prelu(x) @ Wenc^T ; h[mask]=0 ; aggr = segsum(h[src]+emb) ;
//             out = relu(aggr@W1^T+b1) @ W2^T + b2
// N=50000, E=800000, D=128, DFF=256, OUT=119
// ---------------------------------------------------------------------------

// ---- K1: h = prelu(x) @ Wenc^T ------------------------------------------
// 256 threads, 64 nodes/block. Wenc transposed into LDS once per block.
__global__ __launch_bounds__(256) void k_enc(const float* __restrict__ x,
                                             const float* __restrict__ W,
                                             const float* __restrict__ prelu_a,
                                             float* __restrict__ h, int n)
{
    __shared__ float Wt[128 * 128];   // Wt[k*128+j] = W[j*128+k]
    __shared__ float px[2][128];
    for (int i = threadIdx.x; i < 128 * 128; i += 256) {
        int j = i >> 7, k = i & 127;
        Wt[(k << 7) + j] = W[i];
    }
    float a = prelu_a[0];
    __syncthreads();
    int slot = threadIdx.x >> 7;      // 0..1 (two nodes in flight)
    int j    = threadIdx.x & 127;     // output column
    int base = blockIdx.x * 64;
    for (int nn = slot; nn < 64; nn += 2) {
        int node = base + nn;
        float v = 0.f;
        if (node < n) v = x[((size_t)node << 7) + j];
        px[slot][j] = (v > 0.f) ? v : a * v;
        __syncthreads();
        float acc = 0.f;
#pragma unroll 8
        for (int k = 0; k < 128; ++k)
            acc = fmaf(px[slot][k], Wt[(k << 7) + j], acc);
        if (node < n) h[((size_t)node << 7) + j] = acc;
        __syncthreads();
    }
}

// ---- K2: zero masked rows of h (float4 stores) ---------------------------
__global__ void k_mask(const int* __restrict__ midx, float4* __restrict__ h4, int nm)
{
    int idx = blockIdx.x * blockDim.x + threadIdx.x;   // over nm*32
    if (idx >= nm * 32) return;
    int m = idx >> 5, d = idx & 31;
    h4[((size_t)midx[m] << 5) + d] = make_float4(0.f, 0.f, 0.f, 0.f);
}

// ---- K3: aggr = h + emb1[4] + emb2[0]  (self-loop init) ------------------
__global__ void k_init(const float4* __restrict__ h4,
                       const float* __restrict__ emb1,
                       const float* __restrict__ emb2,
                       float4* __restrict__ a4, int n4)
{
    int idx = blockIdx.x * blockDim.x + threadIdx.x;   // over n*32
    if (idx >= n4) return;
    int d = (idx & 31) << 2;
    float4 hv = h4[idx];
    float4 e1 = *(const float4*)(emb1 + 4 * 128 + d);
    float4 e2 = *(const float4*)(emb2 + d);
    hv.x += e1.x + e2.x; hv.y += e1.y + e2.y;
    hv.z += e1.z + e2.z; hv.w += e1.w + e2.w;
    a4[idx] = hv;
}

// ---- K4: edge scatter: aggr[dst] += h[src] + emb1[et] + emb2[ed] ---------
// One wave per edge: 64 lanes x float2 = 128 floats, coalesced.
__global__ __launch_bounds__(256) void k_scatter(const int* __restrict__ ei,
                                                 const int* __restrict__ ea,
                                                 const float* __restrict__ h,
                                                 const float* __restrict__ emb1,
                                                 const float* __restrict__ emb2,
                                                 float* __restrict__ aggr, int E)
{
    int idx = blockIdx.x * 256 + threadIdx.x;          // over E*64
    int e = idx >> 6;
    if (e >= E) return;
    int p = (idx & 63) << 1;                           // dims p, p+1
    int src = ei[e];
    int dst = ei[E + e];
    int et  = ea[2 * e];
    int ed  = ea[2 * e + 1];
    float2 hv = *(const float2*)(h    + ((size_t)src << 7) + p);
    float2 e1 = *(const float2*)(emb1 + (et << 7) + p);
    float2 e2 = *(const float2*)(emb2 + (ed << 7) + p);
    float* dptr = aggr + ((size_t)dst << 7) + p;
    unsafeAtomicAdd(dptr,     hv.x + e1.x + e2.x);
    unsafeAtomicAdd(dptr + 1, hv.y + e1.y + e2.y);
}

// ---- K5: hid = relu(aggr @ W1^T + b1) ------------------------------------
// W1 [256,128] transposed into 128KB LDS; 256 threads = 256 output cols.
__global__ __launch_bounds__(256) void k_mlp1(const float* __restrict__ aggr,
                                              const float* __restrict__ W1,
                                              const float* __restrict__ b1,
                                              float* __restrict__ hid, int n)
{
    __shared__ float Wt[128 * 256];   // Wt[k*256+j] = W1[j*128+k]
    __shared__ float px[128];
    for (int i = threadIdx.x; i < 256 * 128; i += 256) {
        int j = i >> 7, k = i & 127;
        Wt[(k << 8) + j] = W1[i];
    }
    int j = threadIdx.x;
    float bj = b1[j];
    __syncthreads();
    int base = blockIdx.x * 64;
    for (int nn = 0; nn < 64; ++nn) {
        int node = base + nn;
        if (node >= n) break;                    // uniform branch
        if (j < 128) px[j] = aggr[((size_t)node << 7) + j];
        __syncthreads();
        float acc = bj;
#pragma unroll 8
        for (int k = 0; k < 128; ++k)
            acc = fmaf(px[k], Wt[(k << 8) + j], acc);
        hid[((size_t)node << 8) + j] = acc > 0.f ? acc : 0.f;
        __syncthreads();
    }
}

// ---- K6: out = hid @ W2^T + b2 -------------------------------------------
// W2 [119,256] transposed into ~122KB LDS; 2 nodes in flight per block.
__global__ __launch_bounds__(256) void k_mlp2(const float* __restrict__ hid,
                                              const float* __restrict__ W2,
                                              const float* __restrict__ b2,
                                              float* __restrict__ out, int n)
{
    __shared__ float Wt[256 * 119];   // Wt[k*119+j] = W2[j*256+k]
    __shared__ float hx[2][256];
    for (int i = threadIdx.x; i < 119 * 256; i += 256) {
        int j = i >> 8, k = i & 255;
        Wt[k * 119 + j] = W2[i];
    }
    int slot = threadIdx.x >> 7;
    int j    = threadIdx.x & 127;
    int jj   = j < 119 ? j : 0;       // clamp (lanes 119..127 inactive on write)
    float bj = b2[jj];
    __syncthreads();
    int base = blockIdx.x * 64;
    for (int nn = slot; nn < 64; nn += 2) {
        int node = base + nn;
        if (node < n) {
            hx[slot][j]       = hid[((size_t)node << 8) + j];
            hx[slot][j + 128] = hid[((size_t)node << 8) + 128 + j];
        }
        __syncthreads();
        float acc = bj;
#pragma unroll 8
        for (int k = 0; k < 256; ++k)
            acc = fmaf(hx[slot][k], Wt[k * 119 + jj], acc);
        if (node < n && j < 119)
            out[(size_t)node * 119 + j] = acc;
        __syncthreads();
    }
}

extern "C" void kernel_launch(void* const* d_in, const int* in_sizes, int n_in,
                              void* d_out, int out_size, void* d_ws, size_t ws_size,
                              hipStream_t stream)
{
    const float* x    = (const float*)d_in[0];
    const int*   ei   = (const int*)d_in[1];    // [2,E]
    const int*   ea   = (const int*)d_in[2];    // [E,2]
    const int*   midx = (const int*)d_in[3];    // [NM]
    const float* pa   = (const float*)d_in[4];  // scalar
    const float* Wen  = (const float*)d_in[5];  // [128,128]
    const float* emb1 = (const float*)d_in[6];  // [6,128]
    const float* emb2 = (const float*)d_in[7];  // [3,128]
    const float* W1   = (const float*)d_in[8];  // [256,128]
    const float* b1   = (const float*)d_in[9];  // [256]
    const float* W2   = (const float*)d_in[10]; // [119,256]
    const float* b2   = (const float*)d_in[11]; // [119]
    float* out = (float*)d_out;

    int n  = in_sizes[0] / 128;
    int E  = in_sizes[1] / 2;
    int nm = in_sizes[3];

    char* ws = (char*)d_ws;
    float* aggr = (float*)ws;                           // n*128 f32 (25.6 MB)
    float* h    = (float*)(ws + (size_t)n * 128 * 4);   // n*128 f32
    float* hid  = (float*)(ws + (size_t)n * 128 * 4);   // n*256 f32 (reuses h)

    k_enc <<<(n + 63) / 64, 256, 0, stream>>>(x, Wen, pa, h, n);
    k_mask<<<(nm * 32 + 255) / 256, 256, 0, stream>>>(midx, (float4*)h, nm);
    k_init<<<(n * 32 + 255) / 256, 256, 0, stream>>>((const float4*)h, emb1, emb2,
                                                     (float4*)aggr, n * 32);
    k_scatter<<<(E * 64 + 255) / 256, 256, 0, stream>>>(ei, ea, h, emb1, emb2,
                                                        aggr, E);
    k_mlp1<<<(n + 63) / 64, 256, 0, stream>>>(aggr, W1, b1, hid, n);
    k_mlp2<<<(n + 63) / 64, 256, 0, stream>>>(hid, W2, b2, out, n);
}

// Round 2
// 769.024 us; speedup vs baseline: 2.1961x; 2.1961x over previous
//
#include <hip/hip_runtime.h>

// ---------------------------------------------------------------------------
// GNNDecoder: h = prelu(x) @ Wenc^T ; h[mask]=0 ;
//             aggr = segment_sum(h[src]+emb1[et]+emb2[ed]) + selfloop ;
//             out = relu(aggr@W1^T+b1) @ W2^T + b2
// N=50000, E=800000, D=128, DFF=256, OUT=119
// Aggregation via device-built dst-CSR (no float atomics).
// GEMMs: register-tiled (4x8 / 2x8 acc), row-major LDS with +1-row pad.
// ---------------------------------------------------------------------------

// ---- K1: h = prelu(x) @ Wenc^T  (64 nodes x 128 cols per block) ----------
__global__ __launch_bounds__(256) void k_enc(const float* __restrict__ x,
                                             const float* __restrict__ W,
                                             const float* __restrict__ prelu_a,
                                             float* __restrict__ h, int n)
{
    __shared__ float Ws[128 * 129];   // W row-major, row stride 129
    __shared__ float px[64 * 129];    // prelu(x) tile, row stride 129
    int t = threadIdx.x;
    float a = prelu_a[0];
    for (int i = t; i < 128 * 32; i += 256) {          // stage W
        int j = i >> 5, k4 = (i & 31) << 2;
        float4 v = *(const float4*)(W + (j << 7) + k4);
        float* d = Ws + j * 129 + k4;
        d[0] = v.x; d[1] = v.y; d[2] = v.z; d[3] = v.w;
    }
    int base = blockIdx.x * 64;
    for (int i = t; i < 64 * 32; i += 256) {           // stage prelu(x)
        int nn = i >> 5, k4 = (i & 31) << 2;
        int node = base + nn;
        float4 v = make_float4(0.f, 0.f, 0.f, 0.f);
        if (node < n) v = *(const float4*)(x + ((size_t)node << 7) + k4);
        v.x = v.x > 0.f ? v.x : a * v.x;
        v.y = v.y > 0.f ? v.y : a * v.y;
        v.z = v.z > 0.f ? v.z : a * v.z;
        v.w = v.w > 0.f ? v.w : a * v.w;
        float* d = px + nn * 129 + k4;
        d[0] = v.x; d[1] = v.y; d[2] = v.z; d[3] = v.w;
    }
    __syncthreads();
    int ns = t >> 4;                 // 16 strips x 4 nodes
    int cs = t & 15;                 // 16 strips x 8 cols
    const float* pa0 = px + (ns << 2) * 129;
    const float* pw0 = Ws + (cs << 3) * 129;
    float acc[4][8] = {};
#pragma unroll 4
    for (int k = 0; k < 128; ++k) {
        float a0 = pa0[k];
        float a1 = pa0[k + 129];
        float a2 = pa0[k + 258];
        float a3 = pa0[k + 387];
#pragma unroll
        for (int q = 0; q < 8; ++q) {
            float w = pw0[q * 129 + k];
            acc[0][q] = fmaf(a0, w, acc[0][q]);
            acc[1][q] = fmaf(a1, w, acc[1][q]);
            acc[2][q] = fmaf(a2, w, acc[2][q]);
            acc[3][q] = fmaf(a3, w, acc[3][q]);
        }
    }
    int col = cs << 3;
#pragma unroll
    for (int m = 0; m < 4; ++m) {
        int node = base + (ns << 2) + m;
        if (node < n) {
            float* o = h + ((size_t)node << 7) + col;
            *(float4*)(o)     = make_float4(acc[m][0], acc[m][1], acc[m][2], acc[m][3]);
            *(float4*)(o + 4) = make_float4(acc[m][4], acc[m][5], acc[m][6], acc[m][7]);
        }
    }
}

// ---- K2: zero masked rows of h -------------------------------------------
__global__ void k_mask(const int* __restrict__ midx, float4* __restrict__ h4, int nm)
{
    int idx = blockIdx.x * blockDim.x + threadIdx.x;
    if (idx >= nm * 32) return;
    int m = idx >> 5, d = idx & 31;
    h4[((size_t)midx[m] << 5) + d] = make_float4(0.f, 0.f, 0.f, 0.f);
}

// ---- CSR build -----------------------------------------------------------
__global__ void k_hist(const int* __restrict__ ei, int* __restrict__ cnt, int E)
{
    int e = blockIdx.x * blockDim.x + threadIdx.x;
    if (e >= E) return;
    atomicAdd(&cnt[ei[E + e]], 1);
}

__global__ __launch_bounds__(1024) void k_scan(const int* __restrict__ cnt,
                                               int* __restrict__ off,
                                               int* __restrict__ cur, int n)
{
    __shared__ int sbuf[2][1024];
    int t = threadIdx.x;
    int chunk = (n + 1023) >> 10;
    int lo = t * chunk, hi = min(lo + chunk, n);
    int s = 0;
    for (int i = lo; i < hi; ++i) s += cnt[i];
    sbuf[0][t] = s;
    __syncthreads();
    int cb = 0;
    for (int d = 1; d < 1024; d <<= 1) {
        int v = sbuf[cb][t];
        if (t >= d) v += sbuf[cb][t - d];
        sbuf[cb ^ 1][t] = v;
        cb ^= 1;
        __syncthreads();
    }
    int run = (t == 0) ? 0 : sbuf[cb][t - 1];
    for (int i = lo; i < hi; ++i) {
        off[i] = run; cur[i] = run;
        run += cnt[i];
    }
    if (t == 1023) off[n] = sbuf[cb][1023];
}

__global__ void k_fill(const int* __restrict__ ei, const int* __restrict__ ea,
                       int* __restrict__ cur, int* __restrict__ sorted, int E)
{
    int e = blockIdx.x * blockDim.x + threadIdx.x;
    if (e >= E) return;
    int src = ei[e];
    int dst = ei[E + e];
    int et  = ea[2 * e];
    int ed  = ea[2 * e + 1];
    int pos = atomicAdd(&cur[dst], 1);
    sorted[pos] = src | (et << 17) | (ed << 19);
}

// ---- K_agg: one wave per node, gather its edge list ----------------------
__global__ __launch_bounds__(256) void k_agg(const float2* __restrict__ h2,
                                             const int* __restrict__ off,
                                             const int* __restrict__ sorted,
                                             const float* __restrict__ emb1,
                                             const float* __restrict__ emb2,
                                             float2* __restrict__ aggr2, int n)
{
    int lane = threadIdx.x & 63;
    int node = blockIdx.x * 4 + (threadIdx.x >> 6);
    if (node >= n) return;
    int p = lane << 1;
    float2 e10 = *(const float2*)(emb1 + 0 * 128 + p);
    float2 e11 = *(const float2*)(emb1 + 1 * 128 + p);
    float2 e12 = *(const float2*)(emb1 + 2 * 128 + p);
    float2 e14 = *(const float2*)(emb1 + 4 * 128 + p);
    float2 e20 = *(const float2*)(emb2 + 0 * 128 + p);
    float2 e21 = *(const float2*)(emb2 + 1 * 128 + p);
    float2 e22 = *(const float2*)(emb2 + 2 * 128 + p);
    // self loop: h[node] + emb1[4] + emb2[0]
    float2 hv = h2[(size_t)node * 64 + lane];
    float2 acc;
    acc.x = hv.x + e14.x + e20.x;
    acc.y = hv.y + e14.y + e20.y;
    int i0 = off[node], i1 = off[node + 1];
    for (int i = i0; i < i1; ++i) {
        int pk  = sorted[i];
        int src = pk & 0x1FFFF;
        int et  = (pk >> 17) & 3;
        int ed  = (pk >> 19) & 3;
        float2 s = h2[(size_t)src * 64 + lane];
        float2 e1 = (et == 0) ? e10 : (et == 1) ? e11 : e12;
        float2 e2 = (ed == 0) ? e20 : (ed == 1) ? e21 : e22;
        acc.x += s.x + e1.x + e2.x;
        acc.y += s.y + e1.y + e2.y;
    }
    aggr2[(size_t)node * 64 + lane] = acc;
}

// ---- K5: hid = relu(aggr @ W1^T + b1)  (64n x 128c per block, y=half) ----
__global__ __launch_bounds__(256) void k_mlp1(const float* __restrict__ aggr,
                                              const float* __restrict__ W1,
                                              const float* __restrict__ b1,
                                              float* __restrict__ hid, int n)
{
    __shared__ float Ws[128 * 129];
    __shared__ float px[64 * 129];
    int t = threadIdx.x;
    int half = blockIdx.y;           // output-col half
    for (int i = t; i < 128 * 32; i += 256) {
        int j = i >> 5, k4 = (i & 31) << 2;
        float4 v = *(const float4*)(W1 + (((half << 7) + j) << 7) + k4);
        float* d = Ws + j * 129 + k4;
        d[0] = v.x; d[1] = v.y; d[2] = v.z; d[3] = v.w;
    }
    int base = blockIdx.x * 64;
    for (int i = t; i < 64 * 32; i += 256) {
        int nn = i >> 5, k4 = (i & 31) << 2;
        int node = base + nn;
        float4 v = make_float4(0.f, 0.f, 0.f, 0.f);
        if (node < n) v = *(const float4*)(aggr + ((size_t)node << 7) + k4);
        float* d = px + nn * 129 + k4;
        d[0] = v.x; d[1] = v.y; d[2] = v.z; d[3] = v.w;
    }
    __syncthreads();
    int ns = t >> 4;
    int cs = t & 15;
    const float* pa0 = px + (ns << 2) * 129;
    const float* pw0 = Ws + (cs << 3) * 129;
    float acc[4][8] = {};
#pragma unroll 4
    for (int k = 0; k < 128; ++k) {
        float a0 = pa0[k];
        float a1 = pa0[k + 129];
        float a2 = pa0[k + 258];
        float a3 = pa0[k + 387];
#pragma unroll
        for (int q = 0; q < 8; ++q) {
            float w = pw0[q * 129 + k];
            acc[0][q] = fmaf(a0, w, acc[0][q]);
            acc[1][q] = fmaf(a1, w, acc[1][q]);
            acc[2][q] = fmaf(a2, w, acc[2][q]);
            acc[3][q] = fmaf(a3, w, acc[3][q]);
        }
    }
    int col = (half << 7) + (cs << 3);
    float bb[8];
#pragma unroll
    for (int q = 0; q < 8; ++q) bb[q] = b1[col + q];
#pragma unroll
    for (int m = 0; m < 4; ++m) {
        int node = base + (ns << 2) + m;
        if (node < n) {
            float r[8];
#pragma unroll
            for (int q = 0; q < 8; ++q) {
                float v = acc[m][q] + bb[q];
                r[q] = v > 0.f ? v : 0.f;
            }
            float* o = hid + ((size_t)node << 8) + col;
            *(float4*)(o)     = make_float4(r[0], r[1], r[2], r[3]);
            *(float4*)(o + 4) = make_float4(r[4], r[5], r[6], r[7]);
        }
    }
}

// ---- K6: out = hid @ W2^T + b2  (32 nodes x 119 cols per block) ----------
__global__ __launch_bounds__(256) void k_mlp2(const float* __restrict__ hid,
                                              const float* __restrict__ W2,
                                              const float* __restrict__ b2,
                                              float* __restrict__ out, int n)
{
    __shared__ float Ws[119 * 257];
    __shared__ float hx[32 * 257];
    int t = threadIdx.x;
    for (int i = t; i < 119 * 64; i += 256) {
        int j = i >> 6, k4 = (i & 63) << 2;
        float4 v = *(const float4*)(W2 + (j << 8) + k4);
        float* d = Ws + j * 257 + k4;
        d[0] = v.x; d[1] = v.y; d[2] = v.z; d[3] = v.w;
    }
    int base = blockIdx.x * 32;
    for (int i = t; i < 32 * 64; i += 256) {
        int nn = i >> 6, k4 = (i & 63) << 2;
        int node = base + nn;
        float4 v = make_float4(0.f, 0.f, 0.f, 0.f);
        if (node < n) v = *(const float4*)(hid + ((size_t)node << 8) + k4);
        float* d = hx + nn * 257 + k4;
        d[0] = v.x; d[1] = v.y; d[2] = v.z; d[3] = v.w;
    }
    __syncthreads();
    int ns = t >> 4;                 // 16 strips x 2 nodes
    int cs = t & 15;                 // 16 strips x 8 cols (>=119 dead)
    const float* pa = hx + (ns << 1) * 257;
    const float* pw[8];
#pragma unroll
    for (int q = 0; q < 8; ++q) {
        int col = (cs << 3) + q;
        pw[q] = Ws + (col < 119 ? col : 118) * 257;
    }
    float acc[2][8] = {};
#pragma unroll 4
    for (int k = 0; k < 256; ++k) {
        float a0 = pa[k];
        float a1 = pa[k + 257];
#pragma unroll
        for (int q = 0; q < 8; ++q) {
            float w = pw[q][k];
            acc[0][q] = fmaf(a0, w, acc[0][q]);
            acc[1][q] = fmaf(a1, w, acc[1][q]);
        }
    }
#pragma unroll
    for (int m = 0; m < 2; ++m) {
        int node = base + (ns << 1) + m;
        if (node < n) {
#pragma unroll
            for (int q = 0; q < 8; ++q) {
                int col = (cs << 3) + q;
                if (col < 119)
                    out[(size_t)node * 119 + col] = acc[m][q] + b2[col];
            }
        }
    }
}

extern "C" void kernel_launch(void* const* d_in, const int* in_sizes, int n_in,
                              void* d_out, int out_size, void* d_ws, size_t ws_size,
                              hipStream_t stream)
{
    const float* x    = (const float*)d_in[0];
    const int*   ei   = (const int*)d_in[1];    // [2,E]
    const int*   ea   = (const int*)d_in[2];    // [E,2]
    const int*   midx = (const int*)d_in[3];    // [NM]
    const float* pa   = (const float*)d_in[4];  // scalar
    const float* Wen  = (const float*)d_in[5];  // [128,128]
    const float* emb1 = (const float*)d_in[6];  // [6,128]
    const float* emb2 = (const float*)d_in[7];  // [3,128]
    const float* W1   = (const float*)d_in[8];  // [256,128]
    const float* b1   = (const float*)d_in[9];  // [256]
    const float* W2   = (const float*)d_in[10]; // [119,256]
    const float* b2   = (const float*)d_in[11]; // [119]
    float* out = (float*)d_out;

    int n  = in_sizes[0] / 128;
    int E  = in_sizes[1] / 2;
    int nm = in_sizes[3];

    char* ws = (char*)d_ws;
    size_t NB = (size_t)n * 128 * 4;            // 25.6 MB
    float* aggr = (float*)ws;                   // [0, NB)
    float* h    = (float*)(ws + NB);            // [NB, 2NB)
    float* hid  = (float*)(ws + NB);            // [NB, 3NB) after h+CSR are dead
    int*   off  = (int*)(ws + 2 * NB);          // n+1
    int*   cur  = off + (n + 1);                // n+1
    int*   cnt  = cur + (n + 1);                // n
    int*   sorted = cnt + n;                    // E

    hipMemsetAsync(cnt, 0, (size_t)n * 4, stream);

    k_enc <<<(n + 63) / 64, 256, 0, stream>>>(x, Wen, pa, h, n);
    k_mask<<<(nm * 32 + 255) / 256, 256, 0, stream>>>(midx, (float4*)h, nm);
    k_hist<<<(E + 255) / 256, 256, 0, stream>>>(ei, cnt, E);
    k_scan<<<1, 1024, 0, stream>>>(cnt, off, cur, n);
    k_fill<<<(E + 255) / 256, 256, 0, stream>>>(ei, ea, cur, sorted, E);
    k_agg <<<(n + 3) / 4, 256, 0, stream>>>((const float2*)h, off, sorted,
                                            emb1, emb2, (float2*)aggr, n);
    {
        dim3 g((n + 63) / 64, 2);
        k_mlp1<<<g, 256, 0, stream>>>(aggr, W1, b1, hid, n);
    }
    k_mlp2<<<(n + 31) / 32, 256, 0, stream>>>(hid, W2, b2, out, n);
}

// Round 3
// 381.676 us; speedup vs baseline: 4.4249x; 2.0149x over previous
//
#include <hip/hip_runtime.h>

// ---------------------------------------------------------------------------
// GNNDecoder: h = prelu(x) @ Wenc^T ; h[mask]=0 ;
//             aggr = segment_sum(h[src]+emb1[et]+emb2[ed]) + selfloop ;
//             out = relu(aggr@W1^T+b1) @ W2^T + b2
// N=50000, E=800000, D=128, DFF=256, OUT=119
//
// GEMM pattern (all three): 64-row tile, LDS stride 132 floats (16B-aligned,
// 132 % 32 == 4 -> worst 2-way bank aliasing, free), thread = (rs=t>>4)*4 rows
// x cols {cs + 16q} (consecutive cs -> consecutive banks), float4 LDS reads.
// 67.6 KB LDS -> 2 blocks/CU. W-tile loops inside block (W is L2-resident).
// ---------------------------------------------------------------------------

#define LSTR 132   // LDS row stride in floats

__device__ __forceinline__ void gemm_tile_128(const float* __restrict__ pa,
                                              const float* __restrict__ pw,
                                              float acc[4][4])
{
#pragma unroll 4
    for (int kk = 0; kk < 128; kk += 4) {
        float4 av[4], wv[4];
#pragma unroll
        for (int m = 0; m < 4; ++m)
            av[m] = *(const float4*)(pa + m * LSTR + kk);
#pragma unroll
        for (int q = 0; q < 4; ++q)
            wv[q] = *(const float4*)(pw + q * 16 * LSTR + kk);
#pragma unroll
        for (int m = 0; m < 4; ++m)
#pragma unroll
            for (int q = 0; q < 4; ++q) {
                acc[m][q] = fmaf(av[m].x, wv[q].x, acc[m][q]);
                acc[m][q] = fmaf(av[m].y, wv[q].y, acc[m][q]);
                acc[m][q] = fmaf(av[m].z, wv[q].z, acc[m][q]);
                acc[m][q] = fmaf(av[m].w, wv[q].w, acc[m][q]);
            }
    }
}

// ---- K1: h = prelu(x) @ Wenc^T -------------------------------------------
__global__ __launch_bounds__(256) void k_enc(const float* __restrict__ x,
                                             const float* __restrict__ W,
                                             const float* __restrict__ prelu_a,
                                             float* __restrict__ h, int n)
{
    __shared__ float As[64 * LSTR];
    __shared__ float Ws[64 * LSTR];
    int t = threadIdx.x;
    int base = blockIdx.x * 64;
    float a = prelu_a[0];
    for (int i = t; i < 64 * 32; i += 256) {
        int r = i >> 5, k4 = (i & 31) << 2;
        int node = base + r;
        float4 v = make_float4(0.f, 0.f, 0.f, 0.f);
        if (node < n) v = *(const float4*)(x + (((size_t)node) << 7) + k4);
        v.x = v.x > 0.f ? v.x : a * v.x;
        v.y = v.y > 0.f ? v.y : a * v.y;
        v.z = v.z > 0.f ? v.z : a * v.z;
        v.w = v.w > 0.f ? v.w : a * v.w;
        *(float4*)(As + r * LSTR + k4) = v;
    }
    int rs = t >> 4, cs = t & 15;
    const float* pa = As + (rs << 2) * LSTR;
    const float* pw = Ws + cs * LSTR;
    for (int y = 0; y < 2; ++y) {
        __syncthreads();   // y=0: A staged; y>0: prior compute done
        for (int i = t; i < 64 * 32; i += 256) {
            int c = i >> 5, k4 = (i & 31) << 2;
            *(float4*)(Ws + c * LSTR + k4) =
                *(const float4*)(W + (((y << 6) + c) << 7) + k4);
        }
        __syncthreads();
        float acc[4][4] = {};
        gemm_tile_128(pa, pw, acc);
#pragma unroll
        for (int m = 0; m < 4; ++m) {
            int node = base + (rs << 2) + m;
            if (node < n) {
#pragma unroll
                for (int q = 0; q < 4; ++q)
                    h[(((size_t)node) << 7) + (y << 6) + cs + (q << 4)] = acc[m][q];
            }
        }
    }
}

// ---- K2: zero masked rows of h -------------------------------------------
__global__ void k_mask(const int* __restrict__ midx, float4* __restrict__ h4, int nm)
{
    int idx = blockIdx.x * blockDim.x + threadIdx.x;
    if (idx >= nm * 32) return;
    int m = idx >> 5, d = idx & 31;
    h4[((size_t)midx[m] << 5) + d] = make_float4(0.f, 0.f, 0.f, 0.f);
}

// ---- CSR build -----------------------------------------------------------
__global__ void k_hist(const int* __restrict__ ei, int* __restrict__ cnt, int E)
{
    int e = blockIdx.x * blockDim.x + threadIdx.x;
    if (e >= E) return;
    atomicAdd(&cnt[ei[E + e]], 1);
}

__global__ __launch_bounds__(256) void k_part(const int* __restrict__ cnt,
                                              int* __restrict__ part, int n)
{
    __shared__ int sb[256];
    int t = threadIdx.x;
    int i = blockIdx.x * 256 + t;
    sb[t] = i < n ? cnt[i] : 0;
    __syncthreads();
    for (int d = 128; d > 0; d >>= 1) {
        if (t < d) sb[t] += sb[t + d];
        __syncthreads();
    }
    if (t == 0) part[blockIdx.x] = sb[0];
}

__global__ __launch_bounds__(256) void k_scanp(const int* __restrict__ part,
                                               int* __restrict__ pbase,
                                               int* __restrict__ off, int nb, int n)
{
    __shared__ int sb[2][256];
    int t = threadIdx.x;
    int v = t < nb ? part[t] : 0;
    sb[0][t] = v;
    __syncthreads();
    int cb = 0;
    for (int d = 1; d < 256; d <<= 1) {
        int x = sb[cb][t];
        if (t >= d) x += sb[cb][t - d];
        sb[cb ^ 1][t] = x;
        cb ^= 1;
        __syncthreads();
    }
    if (t < nb) pbase[t] = sb[cb][t] - v;          // exclusive base per block
    if (t == 255) off[n] = sb[cb][255];            // total = E
}

__global__ __launch_bounds__(256) void k_off(const int* __restrict__ cnt,
                                             const int* __restrict__ pbase,
                                             int* __restrict__ off,
                                             int* __restrict__ cur, int n)
{
    __shared__ int sb[2][256];
    int t = threadIdx.x;
    int i = blockIdx.x * 256 + t;
    int v = i < n ? cnt[i] : 0;
    sb[0][t] = v;
    __syncthreads();
    int cb = 0;
    for (int d = 1; d < 256; d <<= 1) {
        int x = sb[cb][t];
        if (t >= d) x += sb[cb][t - d];
        sb[cb ^ 1][t] = x;
        cb ^= 1;
        __syncthreads();
    }
    if (i < n) {
        int o = pbase[blockIdx.x] + sb[cb][t] - v;  // exclusive
        off[i] = o;
        cur[i] = o;
    }
}

__global__ void k_fill(const int* __restrict__ ei, const int* __restrict__ ea,
                       int* __restrict__ cur, int* __restrict__ sorted, int E)
{
    int e = blockIdx.x * blockDim.x + threadIdx.x;
    if (e >= E) return;
    int src = ei[e];
    int dst = ei[E + e];
    int et  = ea[2 * e];
    int ed  = ea[2 * e + 1];
    int pos = atomicAdd(&cur[dst], 1);
    sorted[pos] = src | (et << 17) | (ed << 19);
}

// ---- K_agg: one wave per node, gather its edge list ----------------------
__global__ __launch_bounds__(256) void k_agg(const float2* __restrict__ h2,
                                             const int* __restrict__ off,
                                             const int* __restrict__ sorted,
                                             const float* __restrict__ emb1,
                                             const float* __restrict__ emb2,
                                             float2* __restrict__ aggr2, int n)
{
    int lane = threadIdx.x & 63;
    int node = blockIdx.x * 4 + (threadIdx.x >> 6);
    if (node >= n) return;
    int p = lane << 1;
    float2 e10 = *(const float2*)(emb1 + 0 * 128 + p);
    float2 e11 = *(const float2*)(emb1 + 1 * 128 + p);
    float2 e12 = *(const float2*)(emb1 + 2 * 128 + p);
    float2 e14 = *(const float2*)(emb1 + 4 * 128 + p);
    float2 e20 = *(const float2*)(emb2 + 0 * 128 + p);
    float2 e21 = *(const float2*)(emb2 + 1 * 128 + p);
    float2 e22 = *(const float2*)(emb2 + 2 * 128 + p);
    // self loop: h[node] + emb1[4] + emb2[0]
    float2 hv = h2[(size_t)node * 64 + lane];
    float2 acc;
    acc.x = hv.x + e14.x + e20.x;
    acc.y = hv.y + e14.y + e20.y;
    int i0 = off[node], i1 = off[node + 1];
    for (int i = i0; i < i1; ++i) {
        int pk  = sorted[i];
        int src = pk & 0x1FFFF;
        int et  = (pk >> 17) & 3;
        int ed  = (pk >> 19) & 3;
        float2 s = h2[(size_t)src * 64 + lane];
        float2 e1 = (et == 0) ? e10 : (et == 1) ? e11 : e12;
        float2 e2 = (ed == 0) ? e20 : (ed == 1) ? e21 : e22;
        acc.x += s.x + e1.x + e2.x;
        acc.y += s.y + e1.y + e2.y;
    }
    aggr2[(size_t)node * 64 + lane] = acc;
}

// ---- K5: hid = relu(aggr @ W1^T + b1) ------------------------------------
__global__ __launch_bounds__(256) void k_mlp1(const float* __restrict__ aggr,
                                              const float* __restrict__ W1,
                                              const float* __restrict__ b1,
                                              float* __restrict__ hid, int n)
{
    __shared__ float As[64 * LSTR];
    __shared__ float Ws[64 * LSTR];
    int t = threadIdx.x;
    int base = blockIdx.x * 64;
    for (int i = t; i < 64 * 32; i += 256) {
        int r = i >> 5, k4 = (i & 31) << 2;
        int node = base + r;
        float4 v = make_float4(0.f, 0.f, 0.f, 0.f);
        if (node < n) v = *(const float4*)(aggr + (((size_t)node) << 7) + k4);
        *(float4*)(As + r * LSTR + k4) = v;
    }
    int rs = t >> 4, cs = t & 15;
    const float* pa = As + (rs << 2) * LSTR;
    const float* pw = Ws + cs * LSTR;
    for (int y = 0; y < 4; ++y) {
        __syncthreads();
        for (int i = t; i < 64 * 32; i += 256) {
            int c = i >> 5, k4 = (i & 31) << 2;
            *(float4*)(Ws + c * LSTR + k4) =
                *(const float4*)(W1 + (((y << 6) + c) << 7) + k4);
        }
        __syncthreads();
        float acc[4][4] = {};
        gemm_tile_128(pa, pw, acc);
#pragma unroll
        for (int m = 0; m < 4; ++m) {
            int node = base + (rs << 2) + m;
            if (node < n) {
#pragma unroll
                for (int q = 0; q < 4; ++q) {
                    int col = (y << 6) + cs + (q << 4);
                    float v = acc[m][q] + b1[col];
                    hid[(((size_t)node) << 8) + col] = v > 0.f ? v : 0.f;
                }
            }
        }
    }
}

// ---- K6: out = hid @ W2^T + b2  (K=256 in two halves) --------------------
__global__ __launch_bounds__(256) void k_mlp2(const float* __restrict__ hid,
                                              const float* __restrict__ W2,
                                              const float* __restrict__ b2,
                                              float* __restrict__ out, int n)
{
    __shared__ float As[64 * LSTR];
    __shared__ float Ws[64 * LSTR];
    int t = threadIdx.x;
    int base = blockIdx.x * 64;
    int rs = t >> 4, cs = t & 15;
    const float* pa = As + (rs << 2) * LSTR;
    const float* pw = Ws + cs * LSTR;
    float acc[2][4][4] = {};
    for (int kh = 0; kh < 2; ++kh) {
        for (int y = 0; y < 2; ++y) {
            __syncthreads();   // prior compute done before restaging
            if (y == 0) {
                for (int i = t; i < 64 * 32; i += 256) {
                    int r = i >> 5, k4 = (i & 31) << 2;
                    int node = base + r;
                    float4 v = make_float4(0.f, 0.f, 0.f, 0.f);
                    if (node < n)
                        v = *(const float4*)(hid + (((size_t)node) << 8) + (kh << 7) + k4);
                    *(float4*)(As + r * LSTR + k4) = v;
                }
            }
            for (int i = t; i < 64 * 32; i += 256) {
                int c = i >> 5, k4 = (i & 31) << 2;
                int col = (y << 6) + c;
                float4 v = make_float4(0.f, 0.f, 0.f, 0.f);
                if (col < 119)
                    v = *(const float4*)(W2 + (col << 8) + (kh << 7) + k4);
                *(float4*)(Ws + c * LSTR + k4) = v;
            }
            __syncthreads();
            gemm_tile_128(pa, pw, acc[y]);
        }
    }
#pragma unroll
    for (int m = 0; m < 4; ++m) {
        int node = base + (rs << 2) + m;
        if (node >= n) continue;
#pragma unroll
        for (int y = 0; y < 2; ++y)
#pragma unroll
            for (int q = 0; q < 4; ++q) {
                int col = (y << 6) + cs + (q << 4);
                if (col < 119)
                    out[(size_t)node * 119 + col] = acc[y][m][q] + b2[col];
            }
    }
}

extern "C" void kernel_launch(void* const* d_in, const int* in_sizes, int n_in,
                              void* d_out, int out_size, void* d_ws, size_t ws_size,
                              hipStream_t stream)
{
    const float* x    = (const float*)d_in[0];
    const int*   ei   = (const int*)d_in[1];    // [2,E]
    const int*   ea   = (const int*)d_in[2];    // [E,2]
    const int*   midx = (const int*)d_in[3];    // [NM]
    const float* pa   = (const float*)d_in[4];  // scalar
    const float* Wen  = (const float*)d_in[5];  // [128,128]
    const float* emb1 = (const float*)d_in[6];  // [6,128]
    const float* emb2 = (const float*)d_in[7];  // [3,128]
    const float* W1   = (const float*)d_in[8];  // [256,128]
    const float* b1   = (const float*)d_in[9];  // [256]
    const float* W2   = (const float*)d_in[10]; // [119,256]
    const float* b2   = (const float*)d_in[11]; // [119]
    float* out = (float*)d_out;

    int n  = in_sizes[0] / 128;
    int E  = in_sizes[1] / 2;
    int nm = in_sizes[3];

    char* ws = (char*)d_ws;
    size_t NB = (size_t)n * 128 * 4;            // 25.6 MB
    float* aggr = (float*)ws;                   // [0, NB)
    float* h    = (float*)(ws + NB);            // [NB, 2NB)
    float* hid  = (float*)(ws + NB);            // [NB, 3NB) after h+CSR dead
    int*   off  = (int*)(ws + 2 * NB);          // n+1
    int*   cur  = off + (n + 1);                // n+1
    int*   cnt  = cur + (n + 1);                // n
    int*   sorted = cnt + n;                    // E
    int*   part   = sorted + E;                 // nb
    int*   pbase  = part + 256;                 // nb

    int nb = (n + 255) / 256;                   // 196 (<=256 required)

    hipMemsetAsync(cnt, 0, (size_t)n * 4, stream);

    k_enc  <<<(n + 63) / 64, 256, 0, stream>>>(x, Wen, pa, h, n);
    k_mask <<<(nm * 32 + 255) / 256, 256, 0, stream>>>(midx, (float4*)h, nm);
    k_hist <<<(E + 255) / 256, 256, 0, stream>>>(ei, cnt, E);
    k_part <<<nb, 256, 0, stream>>>(cnt, part, n);
    k_scanp<<<1, 256, 0, stream>>>(part, pbase, off, nb, n);
    k_off  <<<nb, 256, 0, stream>>>(cnt, pbase, off, cur, n);
    k_fill <<<(E + 255) / 256, 256, 0, stream>>>(ei, ea, cur, sorted, E);
    k_agg  <<<(n + 3) / 4, 256, 0, stream>>>((const float2*)h, off, sorted,
                                             emb1, emb2, (float2*)aggr, n);
    k_mlp1 <<<(n + 63) / 64, 256, 0, stream>>>(aggr, W1, b1, hid, n);
    k_mlp2 <<<(n + 63) / 64, 256, 0, stream>>>(hid, W2, b2, out, n);
}

// Round 4
// 332.132 us; speedup vs baseline: 5.0850x; 1.1492x over previous
//
#include <hip/hip_runtime.h>
#include <hip/hip_fp16.h>

// ---------------------------------------------------------------------------
// GNNDecoder: h = prelu(x) @ Wenc^T (stored fp16); h[mask]=0 ;
//             aggr = sum_{edges->dst} h16[src]  + emb-correction-from-counts
//                    + selfloop(h16[dst]+emb1[4]+emb2[0]) ;
//             out = relu(aggr@W1^T+b1) @ W2^T + b2
// N=50000, E=800000, D=128, DFF=256, OUT=119
//
// emb trick: aggr's emb part = cnt_et0*emb1[0]+cnt_et1*emb1[1]+cnt_et2*emb1[2]
//            + cnt_ed0*emb2[0]+..., counts kept as 6x10-bit fields in one
//            u64 histogram (one 64-bit atomicAdd per edge). Edge loop is then
//            a pure fp16 gather-accumulate.
// ---------------------------------------------------------------------------

#define LSTR 132   // LDS row stride in floats (132%32==4 -> worst 2-way, free)
typedef unsigned long long ull;

__device__ __forceinline__ void gemm_tile_128(const float* __restrict__ pa,
                                              const float* __restrict__ pw,
                                              float acc[4][4])
{
#pragma unroll 4
    for (int kk = 0; kk < 128; kk += 4) {
        float4 av[4], wv[4];
#pragma unroll
        for (int m = 0; m < 4; ++m)
            av[m] = *(const float4*)(pa + m * LSTR + kk);
#pragma unroll
        for (int q = 0; q < 4; ++q)
            wv[q] = *(const float4*)(pw + q * 16 * LSTR + kk);
#pragma unroll
        for (int m = 0; m < 4; ++m)
#pragma unroll
            for (int q = 0; q < 4; ++q) {
                acc[m][q] = fmaf(av[m].x, wv[q].x, acc[m][q]);
                acc[m][q] = fmaf(av[m].y, wv[q].y, acc[m][q]);
                acc[m][q] = fmaf(av[m].z, wv[q].z, acc[m][q]);
                acc[m][q] = fmaf(av[m].w, wv[q].w, acc[m][q]);
            }
    }
}

// ---- K_pre: block-split fusion of {enc: h16 = prelu(x)@Wenc^T} and
// ----        {hist: 64-bit et/ed histogram per dst} (independent work) -----
__global__ __launch_bounds__(256) void k_pre(const float* __restrict__ x,
                                             const float* __restrict__ W,
                                             const float* __restrict__ prelu_a,
                                             __half* __restrict__ h16,
                                             const int* __restrict__ ei,
                                             const int* __restrict__ ea,
                                             ull* __restrict__ cnt64,
                                             int n, int E, int nbEnc, int nbHist)
{
    __shared__ float As[64 * LSTR];
    __shared__ float Ws[64 * LSTR];
    int t = threadIdx.x;

    if ((int)blockIdx.x >= nbEnc) {          // ---- histogram blocks ----
        int b = blockIdx.x - nbEnc;
        for (int e = b * 256 + t; e < E; e += nbHist * 256) {
            int dst = ei[E + e];
            int et  = ea[2 * e];
            int ed  = ea[2 * e + 1];
            atomicAdd(&cnt64[dst], (1ULL << (10 * et)) | (1ULL << (30 + 10 * ed)));
        }
        return;
    }

    // ---- encoder blocks ----
    int base = blockIdx.x * 64;
    float a = prelu_a[0];
    for (int i = t; i < 64 * 32; i += 256) {
        int r = i >> 5, k4 = (i & 31) << 2;
        int node = base + r;
        float4 v = make_float4(0.f, 0.f, 0.f, 0.f);
        if (node < n) v = *(const float4*)(x + (((size_t)node) << 7) + k4);
        v.x = v.x > 0.f ? v.x : a * v.x;
        v.y = v.y > 0.f ? v.y : a * v.y;
        v.z = v.z > 0.f ? v.z : a * v.z;
        v.w = v.w > 0.f ? v.w : a * v.w;
        *(float4*)(As + r * LSTR + k4) = v;
    }
    int rs = t >> 4, cs = t & 15;
    const float* pa = As + (rs << 2) * LSTR;
    const float* pw = Ws + cs * LSTR;
    for (int y = 0; y < 2; ++y) {
        __syncthreads();                     // As staged / prior pass done
        for (int i = t; i < 64 * 32; i += 256) {
            int c = i >> 5, k4 = (i & 31) << 2;
            *(float4*)(Ws + c * LSTR + k4) =
                *(const float4*)(W + (((y << 6) + c) << 7) + k4);
        }
        __syncthreads();
        float acc[4][4] = {};
        gemm_tile_128(pa, pw, acc);
        __syncthreads();                     // all gemm reads of Ws done
        // stage acc -> Ws as 64x64 f32, stride 68 (2-way aliasing, free)
#pragma unroll
        for (int m = 0; m < 4; ++m)
#pragma unroll
            for (int q = 0; q < 4; ++q)
                Ws[((rs << 2) + m) * 68 + cs + (q << 4)] = acc[m][q];
        __syncthreads();
        // coalesced fp16 store: thread t -> row t>>2, 16 cols at (t&3)*16
        {
            int r = t >> 2, c0 = (t & 3) << 4;
            int node = base + r;
            if (node < n) {
                __half2 pk[8];
#pragma unroll
                for (int u = 0; u < 8; ++u)
                    pk[u] = __floats2half2_rn(Ws[r * 68 + c0 + 2 * u],
                                              Ws[r * 68 + c0 + 2 * u + 1]);
                __half* dp = h16 + (((size_t)node) << 7) + (y << 6) + c0;
                *(uint4*)(dp)     = *(uint4*)(pk);
                *(uint4*)(dp + 8) = *(uint4*)(pk + 4);
            }
        }
    }
}

// ---- K2: zero masked rows of h16 (64 uints per row) ----------------------
__global__ void k_mask(const int* __restrict__ midx,
                       unsigned int* __restrict__ h16u, int nm)
{
    int idx = blockIdx.x * blockDim.x + threadIdx.x;
    if (idx >= nm * 64) return;
    int m = idx >> 6, l = idx & 63;
    h16u[(((size_t)midx[m]) << 6) + l] = 0u;
}

// ---- K_alloc: off/cur via wave-scan of degrees + 1 atomic per wave -------
__global__ __launch_bounds__(256) void k_alloc(const ull* __restrict__ cnt64,
                                               int* __restrict__ off,
                                               int* __restrict__ cur,
                                               int* __restrict__ cursor, int n)
{
    int t = blockIdx.x * 256 + threadIdx.x;
    int lane = threadIdx.x & 63;
    int deg = 0;
    if (t < n) {
        ull c = cnt64[t];
        deg = (int)((c & 1023) + ((c >> 10) & 1023) + ((c >> 20) & 1023));
    }
    int s = deg;
    for (int d = 1; d < 64; d <<= 1) {
        int v = __shfl_up(s, d);
        if (lane >= d) s += v;
    }
    int tot = __shfl(s, 63);
    int base = 0;
    if (lane == 0) base = atomicAdd(cursor, tot);
    base = __shfl(base, 0);
    if (t < n) {
        int pos = base + s - deg;            // exclusive within wave
        off[t] = pos;
        cur[t] = pos;
    }
}

// ---- K_fill: bucket src by dst -------------------------------------------
__global__ void k_fill(const int* __restrict__ ei, int* __restrict__ cur,
                       int* __restrict__ sorted, int E)
{
    int e = blockIdx.x * blockDim.x + threadIdx.x;
    if (e >= E) return;
    int src = ei[e];
    int dst = ei[E + e];
    sorted[atomicAdd(&cur[dst], 1)] = src;
}

// ---- K_agg: one wave per node, pure fp16 gather-accumulate ---------------
__global__ __launch_bounds__(256) void k_agg(const unsigned int* __restrict__ h16u,
                                             const int* __restrict__ off,
                                             const ull* __restrict__ cnt64,
                                             const int* __restrict__ sorted,
                                             const float* __restrict__ emb1,
                                             const float* __restrict__ emb2,
                                             float2* __restrict__ aggr2, int n)
{
    int lane = threadIdx.x & 63;
    int node = blockIdx.x * 4 + (threadIdx.x >> 6);
    if (node >= n) return;
    int p = lane << 1;
    float2 e10 = *(const float2*)(emb1 + 0 * 128 + p);
    float2 e11 = *(const float2*)(emb1 + 1 * 128 + p);
    float2 e12 = *(const float2*)(emb1 + 2 * 128 + p);
    float2 e14 = *(const float2*)(emb1 + 4 * 128 + p);
    float2 e20 = *(const float2*)(emb2 + 0 * 128 + p);
    float2 e21 = *(const float2*)(emb2 + 1 * 128 + p);
    float2 e22 = *(const float2*)(emb2 + 2 * 128 + p);

    ull c = cnt64[node];
    float c0 = (float)(c & 1023), c1 = (float)((c >> 10) & 1023),
          c2 = (float)((c >> 20) & 1023);
    float d0 = (float)((c >> 30) & 1023), d1 = (float)((c >> 40) & 1023),
          d2 = (float)((c >> 50) & 1023);
    int deg = (int)(c & 1023) + (int)((c >> 10) & 1023) + (int)((c >> 20) & 1023);

    unsigned int hv = h16u[(((size_t)node) << 6) + lane];
    float2 hf = __half22float2(*(__half2*)&hv);
    // self loop (emb1[4]+emb2[0]) + count-weighted edge embeddings
    float2 acc, acc2 = make_float2(0.f, 0.f);
    acc.x = hf.x + e14.x + e20.x;
    acc.y = hf.y + e14.y + e20.y;
    acc.x = fmaf(c0, e10.x, fmaf(c1, e11.x, fmaf(c2, e12.x, acc.x)));
    acc.y = fmaf(c0, e10.y, fmaf(c1, e11.y, fmaf(c2, e12.y, acc.y)));
    acc.x = fmaf(d0, e20.x, fmaf(d1, e21.x, fmaf(d2, e22.x, acc.x)));
    acc.y = fmaf(d0, e20.y, fmaf(d1, e21.y, fmaf(d2, e22.y, acc.y)));

    int i = off[node], e = i + deg;
    for (; i + 1 < e; i += 2) {
        int s0 = sorted[i], s1 = sorted[i + 1];
        unsigned int v0 = h16u[(((size_t)s0) << 6) + lane];
        unsigned int v1 = h16u[(((size_t)s1) << 6) + lane];
        float2 f0 = __half22float2(*(__half2*)&v0);
        float2 f1 = __half22float2(*(__half2*)&v1);
        acc.x += f0.x;  acc.y += f0.y;
        acc2.x += f1.x; acc2.y += f1.y;
    }
    if (i < e) {
        int s0 = sorted[i];
        unsigned int v0 = h16u[(((size_t)s0) << 6) + lane];
        float2 f0 = __half22float2(*(__half2*)&v0);
        acc.x += f0.x; acc.y += f0.y;
    }
    acc.x += acc2.x; acc.y += acc2.y;
    aggr2[(size_t)node * 64 + lane] = acc;
}

// ---- K5: hid = relu(aggr @ W1^T + b1) ------------------------------------
__global__ __launch_bounds__(256) void k_mlp1(const float* __restrict__ aggr,
                                              const float* __restrict__ W1,
                                              const float* __restrict__ b1,
                                              float* __restrict__ hid, int n)
{
    __shared__ float As[64 * LSTR];
    __shared__ float Ws[64 * LSTR];
    int t = threadIdx.x;
    int base = blockIdx.x * 64;
    for (int i = t; i < 64 * 32; i += 256) {
        int r = i >> 5, k4 = (i & 31) << 2;
        int node = base + r;
        float4 v = make_float4(0.f, 0.f, 0.f, 0.f);
        if (node < n) v = *(const float4*)(aggr + (((size_t)node) << 7) + k4);
        *(float4*)(As + r * LSTR + k4) = v;
    }
    int rs = t >> 4, cs = t & 15;
    const float* pa = As + (rs << 2) * LSTR;
    const float* pw = Ws + cs * LSTR;
    for (int y = 0; y < 4; ++y) {
        __syncthreads();
        for (int i = t; i < 64 * 32; i += 256) {
            int c = i >> 5, k4 = (i & 31) << 2;
            *(float4*)(Ws + c * LSTR + k4) =
                *(const float4*)(W1 + (((y << 6) + c) << 7) + k4);
        }
        __syncthreads();
        float acc[4][4] = {};
        gemm_tile_128(pa, pw, acc);
#pragma unroll
        for (int m = 0; m < 4; ++m) {
            int node = base + (rs << 2) + m;
            if (node < n) {
#pragma unroll
                for (int q = 0; q < 4; ++q) {
                    int col = (y << 6) + cs + (q << 4);
                    float v = acc[m][q] + b1[col];
                    hid[(((size_t)node) << 8) + col] = v > 0.f ? v : 0.f;
                }
            }
        }
    }
}

// ---- K6: out = hid @ W2^T + b2  (K=256 in two halves) --------------------
__global__ __launch_bounds__(256) void k_mlp2(const float* __restrict__ hid,
                                              const float* __restrict__ W2,
                                              const float* __restrict__ b2,
                                              float* __restrict__ out, int n)
{
    __shared__ float As[64 * LSTR];
    __shared__ float Ws[64 * LSTR];
    int t = threadIdx.x;
    int base = blockIdx.x * 64;
    int rs = t >> 4, cs = t & 15;
    const float* pa = As + (rs << 2) * LSTR;
    const float* pw = Ws + cs * LSTR;
    float acc[2][4][4] = {};
    for (int kh = 0; kh < 2; ++kh) {
        for (int y = 0; y < 2; ++y) {
            __syncthreads();
            if (y == 0) {
                for (int i = t; i < 64 * 32; i += 256) {
                    int r = i >> 5, k4 = (i & 31) << 2;
                    int node = base + r;
                    float4 v = make_float4(0.f, 0.f, 0.f, 0.f);
                    if (node < n)
                        v = *(const float4*)(hid + (((size_t)node) << 8) + (kh << 7) + k4);
                    *(float4*)(As + r * LSTR + k4) = v;
                }
            }
            for (int i = t; i < 64 * 32; i += 256) {
                int c = i >> 5, k4 = (i & 31) << 2;
                int col = (y << 6) + c;
                float4 v = make_float4(0.f, 0.f, 0.f, 0.f);
                if (col < 119)
                    v = *(const float4*)(W2 + (col << 8) + (kh << 7) + k4);
                *(float4*)(Ws + c * LSTR + k4) = v;
            }
            __syncthreads();
            gemm_tile_128(pa, pw, acc[y]);
        }
    }
#pragma unroll
    for (int m = 0; m < 4; ++m) {
        int node = base + (rs << 2) + m;
        if (node >= n) continue;
#pragma unroll
        for (int y = 0; y < 2; ++y)
#pragma unroll
            for (int q = 0; q < 4; ++q) {
                int col = (y << 6) + cs + (q << 4);
                if (col < 119)
                    out[(size_t)node * 119 + col] = acc[y][m][q] + b2[col];
            }
    }
}

extern "C" void kernel_launch(void* const* d_in, const int* in_sizes, int n_in,
                              void* d_out, int out_size, void* d_ws, size_t ws_size,
                              hipStream_t stream)
{
    const float* x    = (const float*)d_in[0];
    const int*   ei   = (const int*)d_in[1];    // [2,E]
    const int*   ea   = (const int*)d_in[2];    // [E,2]
    const int*   midx = (const int*)d_in[3];    // [NM]
    const float* pa   = (const float*)d_in[4];  // scalar
    const float* Wen  = (const float*)d_in[5];  // [128,128]
    const float* emb1 = (const float*)d_in[6];  // [6,128]
    const float* emb2 = (const float*)d_in[7];  // [3,128]
    const float* W1   = (const float*)d_in[8];  // [256,128]
    const float* b1   = (const float*)d_in[9];  // [256]
    const float* W2   = (const float*)d_in[10]; // [119,256]
    const float* b2   = (const float*)d_in[11]; // [119]
    float* out = (float*)d_out;

    int n  = in_sizes[0] / 128;
    int E  = in_sizes[1] / 2;
    int nm = in_sizes[3];

    char* ws = (char*)d_ws;
    size_t NB = (size_t)n * 128 * 4;            // 25.6 MB
    float*  aggr = (float*)ws;                  // [0, NB)
    __half* h16  = (__half*)(ws + NB);          // [NB, 1.5NB)
    char* p = ws + NB + NB / 2;
    ull* cnt64  = (ull*)p;      p += (size_t)n * 8;
    int* cursor = (int*)p;      p += 256;
    int* off    = (int*)p;      p += (size_t)n * 4;
    int* cur    = (int*)p;      p += (size_t)n * 4;
    int* sorted = (int*)p;      p += (size_t)E * 4;   // ends ~42.5 MB
    float* hid  = (float*)(ws + NB);            // [NB, 3NB) overlays h16+CSR
                                                // (both dead after k_agg)

    int nbEnc  = (n + 63) / 64;
    int nbHist = 512;

    hipMemsetAsync(cnt64, 0, (size_t)n * 8 + 256, stream);  // cnt64 + cursor

    k_pre  <<<nbEnc + nbHist, 256, 0, stream>>>(x, Wen, pa, h16, ei, ea,
                                                cnt64, n, E, nbEnc, nbHist);
    k_mask <<<(nm * 64 + 255) / 256, 256, 0, stream>>>(midx, (unsigned int*)h16, nm);
    k_alloc<<<(n + 255) / 256, 256, 0, stream>>>(cnt64, off, cur, cursor, n);
    k_fill <<<(E + 255) / 256, 256, 0, stream>>>(ei, cur, sorted, E);
    k_agg  <<<(n + 3) / 4, 256, 0, stream>>>((const unsigned int*)h16, off, cnt64,
                                             sorted, emb1, emb2, (float2*)aggr, n);
    k_mlp1 <<<(n + 63) / 64, 256, 0, stream>>>(aggr, W1, b1, hid, n);
    k_mlp2 <<<(n + 63) / 64, 256, 0, stream>>>(hid, W2, b2, out, n);
}

// Round 5
// 266.967 us; speedup vs baseline: 6.3262x; 1.2441x over previous
//
#include <hip/hip_runtime.h>
#include <hip/hip_fp16.h>

// ---------------------------------------------------------------------------
// GNNDecoder: h16 = fp16( prelu(x) @ Wenc^T ) ; h16[mask]=0 ;
//   aggr16 = fp16( sum_{edges->dst} h16[src] + selfloop + count-weighted emb );
//   hid16  = fp16( relu(aggr16 @ W1^T + b1) ) ;  out = hid16 @ W2^T + b2
// N=50000, E=800000, D=128, DFF=256, OUT=119
//
// All GEMMs: v_mfma_f32_16x16x32_f16, fp32 accum. Activations & weights both
// row-major [row][k] fp16 -> A and B fragments are single 16B loads per lane:
//   A[m = l&15][k = ks*32 + (l>>4)*8 + j],  B[n = l&15][same k]
//   D: col = l&15, row = (l>>4)*4 + reg     (m89-verified mapping)
// emb trick: per-dst 6x10-bit count histogram (1 u64 atomic/edge); edge loop
// is a pure fp16 gather-accumulate.
// ---------------------------------------------------------------------------

typedef unsigned long long ull;
typedef _Float16 half8 __attribute__((ext_vector_type(8)));
typedef float    f32x4 __attribute__((ext_vector_type(4)));

#define MFMA16(a, b, c) __builtin_amdgcn_mfma_f32_16x16x32_f16(a, b, c, 0, 0, 0)

// ---- K_wconv: fp32 -> fp16 weight conversion (W2 padded to 128 rows) -----
__global__ __launch_bounds__(256) void k_wconv(const float* __restrict__ Wen,
                                               const float* __restrict__ W1,
                                               const float* __restrict__ W2,
                                               __half* __restrict__ Wen16,
                                               __half* __restrict__ W1_16,
                                               __half* __restrict__ W2_16p)
{
    int i = blockIdx.x * 256 + threadIdx.x;
    if (i < 128 * 128) Wen16[i] = __float2half(Wen[i]);
    if (i < 256 * 128) W1_16[i] = __float2half(W1[i]);
    if (i < 128 * 256) {
        int r = i >> 8;                       // output col 0..127
        W2_16p[i] = (r < 119) ? __float2half(W2[i]) : __half(0.0f);
    }
}

// ---- K_pre: {enc: h16 = prelu(x)@Wenc^T via MFMA} + {hist} fused ---------
__global__ __launch_bounds__(256) void k_pre(const float* __restrict__ x,
                                             const __half* __restrict__ Wen16,
                                             const float* __restrict__ prelu_a,
                                             __half* __restrict__ h16,
                                             const int* __restrict__ ei,
                                             const int* __restrict__ ea,
                                             ull* __restrict__ cnt64,
                                             int n, int E, int nbEnc, int nbHist)
{
    int t = threadIdx.x;
    if ((int)blockIdx.x >= nbEnc) {          // ---- histogram blocks ----
        int b = blockIdx.x - nbEnc;
        for (int e = b * 256 + t; e < E; e += nbHist * 256) {
            int dst = ei[E + e];
            int et  = ea[2 * e];
            int ed  = ea[2 * e + 1];
            atomicAdd(&cnt64[dst], (1ULL << (10 * et)) | (1ULL << (30 + 10 * ed)));
        }
        return;
    }
    // ---- encoder blocks: 4 waves x 16 rows, 128 cols, K=128 ----
    int lane = t & 63;
    int rowbase = blockIdx.x * 64 + (t >> 6) * 16;
    int mr = rowbase + (lane & 15);
    if (mr >= n) mr = n - 1;                 // clamp (stores guarded)
    int kg = (lane >> 4) * 8;
    float a = prelu_a[0];
    f32x4 acc[8] = {};
#pragma unroll
    for (int ks = 0; ks < 4; ++ks) {
        const float* xp = x + ((size_t)mr << 7) + ks * 32 + kg;
        float4 v0 = *(const float4*)(xp);
        float4 v1 = *(const float4*)(xp + 4);
        half8 af;
        af[0] = (_Float16)(v0.x > 0.f ? v0.x : a * v0.x);
        af[1] = (_Float16)(v0.y > 0.f ? v0.y : a * v0.y);
        af[2] = (_Float16)(v0.z > 0.f ? v0.z : a * v0.z);
        af[3] = (_Float16)(v0.w > 0.f ? v0.w : a * v0.w);
        af[4] = (_Float16)(v1.x > 0.f ? v1.x : a * v1.x);
        af[5] = (_Float16)(v1.y > 0.f ? v1.y : a * v1.y);
        af[6] = (_Float16)(v1.z > 0.f ? v1.z : a * v1.z);
        af[7] = (_Float16)(v1.w > 0.f ? v1.w : a * v1.w);
#pragma unroll
        for (int ct = 0; ct < 8; ++ct) {
            half8 bf = *(const half8*)(Wen16 + (((ct << 4) + (lane & 15)) << 7)
                                             + ks * 32 + kg);
            acc[ct] = MFMA16(af, bf, acc[ct]);
        }
    }
#pragma unroll
    for (int ct = 0; ct < 8; ++ct)
#pragma unroll
        for (int r = 0; r < 4; ++r) {
            int node = rowbase + ((lane >> 4) << 2) + r;
            if (node < n)
                h16[((size_t)node << 7) + (ct << 4) + (lane & 15)] =
                    __float2half(acc[ct][r]);
        }
}

// ---- K2: zero masked rows of h16 (64 uints per row) ----------------------
__global__ void k_mask(const int* __restrict__ midx,
                       unsigned int* __restrict__ h16u, int nm)
{
    int idx = blockIdx.x * blockDim.x + threadIdx.x;
    if (idx >= nm * 64) return;
    int m = idx >> 6, l = idx & 63;
    h16u[(((size_t)midx[m]) << 6) + l] = 0u;
}

// ---- K_alloc: off/cur via wave-scan of degrees + 1 atomic per wave -------
__global__ __launch_bounds__(256) void k_alloc(const ull* __restrict__ cnt64,
                                               int* __restrict__ off,
                                               int* __restrict__ cur,
                                               int* __restrict__ cursor, int n)
{
    int t = blockIdx.x * 256 + threadIdx.x;
    int lane = threadIdx.x & 63;
    int deg = 0;
    if (t < n) {
        ull c = cnt64[t];
        deg = (int)((c & 1023) + ((c >> 10) & 1023) + ((c >> 20) & 1023));
    }
    int s = deg;
    for (int d = 1; d < 64; d <<= 1) {
        int v = __shfl_up(s, d);
        if (lane >= d) s += v;
    }
    int tot = __shfl(s, 63);
    int base = 0;
    if (lane == 0) base = atomicAdd(cursor, tot);
    base = __shfl(base, 0);
    if (t < n) {
        int pos = base + s - deg;
        off[t] = pos;
        cur[t] = pos;
    }
}

// ---- K_fill: bucket src by dst -------------------------------------------
__global__ void k_fill(const int* __restrict__ ei, int* __restrict__ cur,
                       int* __restrict__ sorted, int E)
{
    int e = blockIdx.x * blockDim.x + threadIdx.x;
    if (e >= E) return;
    int src = ei[e];
    int dst = ei[E + e];
    sorted[atomicAdd(&cur[dst], 1)] = src;
}

// ---- K_agg: one wave per node, pure fp16 gather-accumulate ---------------
__global__ __launch_bounds__(256) void k_agg(const unsigned int* __restrict__ h16u,
                                             const int* __restrict__ off,
                                             const ull* __restrict__ cnt64,
                                             const int* __restrict__ sorted,
                                             const float* __restrict__ emb1,
                                             const float* __restrict__ emb2,
                                             unsigned int* __restrict__ aggr16u,
                                             int n)
{
    int lane = threadIdx.x & 63;
    int node = blockIdx.x * 4 + (threadIdx.x >> 6);
    if (node >= n) return;
    int p = lane << 1;
    float2 e10 = *(const float2*)(emb1 + 0 * 128 + p);
    float2 e11 = *(const float2*)(emb1 + 1 * 128 + p);
    float2 e12 = *(const float2*)(emb1 + 2 * 128 + p);
    float2 e14 = *(const float2*)(emb1 + 4 * 128 + p);
    float2 e20 = *(const float2*)(emb2 + 0 * 128 + p);
    float2 e21 = *(const float2*)(emb2 + 1 * 128 + p);
    float2 e22 = *(const float2*)(emb2 + 2 * 128 + p);

    ull c = cnt64[node];
    float c0 = (float)(c & 1023), c1 = (float)((c >> 10) & 1023),
          c2 = (float)((c >> 20) & 1023);
    float d0 = (float)((c >> 30) & 1023), d1 = (float)((c >> 40) & 1023),
          d2 = (float)((c >> 50) & 1023);
    int deg = (int)(c & 1023) + (int)((c >> 10) & 1023) + (int)((c >> 20) & 1023);

    unsigned int hv = h16u[(((size_t)node) << 6) + lane];
    float2 hf = __half22float2(*(__half2*)&hv);
    float2 acc, acc2 = make_float2(0.f, 0.f);
    acc.x = hf.x + e14.x + e20.x;
    acc.y = hf.y + e14.y + e20.y;
    acc.x = fmaf(c0, e10.x, fmaf(c1, e11.x, fmaf(c2, e12.x, acc.x)));
    acc.y = fmaf(c0, e10.y, fmaf(c1, e11.y, fmaf(c2, e12.y, acc.y)));
    acc.x = fmaf(d0, e20.x, fmaf(d1, e21.x, fmaf(d2, e22.x, acc.x)));
    acc.y = fmaf(d0, e20.y, fmaf(d1, e21.y, fmaf(d2, e22.y, acc.y)));

    int i = off[node], e = i + deg;
    for (; i + 1 < e; i += 2) {
        int s0 = sorted[i], s1 = sorted[i + 1];
        unsigned int v0 = h16u[(((size_t)s0) << 6) + lane];
        unsigned int v1 = h16u[(((size_t)s1) << 6) + lane];
        float2 f0 = __half22float2(*(__half2*)&v0);
        float2 f1 = __half22float2(*(__half2*)&v1);
        acc.x += f0.x;  acc.y += f0.y;
        acc2.x += f1.x; acc2.y += f1.y;
    }
    if (i < e) {
        int s0 = sorted[i];
        unsigned int v0 = h16u[(((size_t)s0) << 6) + lane];
        float2 f0 = __half22float2(*(__half2*)&v0);
        acc.x += f0.x; acc.y += f0.y;
    }
    acc.x += acc2.x; acc.y += acc2.y;
    __half2 o = __floats2half2_rn(acc.x, acc.y);
    aggr16u[(size_t)node * 64 + lane] = *(unsigned int*)&o;
}

// ---- K5: hid16 = relu(aggr16 @ W1^T + b1), MFMA --------------------------
__global__ __launch_bounds__(256) void k_mlp1(const __half* __restrict__ aggr16,
                                              const __half* __restrict__ W1_16,
                                              const float* __restrict__ b1,
                                              __half* __restrict__ hid16, int n)
{
    int t = threadIdx.x, lane = t & 63;
    int rowbase = blockIdx.x * 64 + (t >> 6) * 16;
    int mr = rowbase + (lane & 15);
    if (mr >= n) mr = n - 1;
    int kg = (lane >> 4) * 8;
    f32x4 acc[16] = {};
#pragma unroll
    for (int ks = 0; ks < 4; ++ks) {
        half8 af = *(const half8*)(aggr16 + ((size_t)mr << 7) + ks * 32 + kg);
#pragma unroll
        for (int ct = 0; ct < 16; ++ct) {
            half8 bf = *(const half8*)(W1_16 + (((ct << 4) + (lane & 15)) << 7)
                                             + ks * 32 + kg);
            acc[ct] = MFMA16(af, bf, acc[ct]);
        }
    }
#pragma unroll
    for (int ct = 0; ct < 16; ++ct) {
        int col = (ct << 4) + (lane & 15);
        float bb = b1[col];
#pragma unroll
        for (int r = 0; r < 4; ++r) {
            int node = rowbase + ((lane >> 4) << 2) + r;
            if (node < n) {
                float v = acc[ct][r] + bb;
                hid16[((size_t)node << 8) + col] = __float2half(v > 0.f ? v : 0.f);
            }
        }
    }
}

// ---- K6: out = hid16 @ W2^T + b2, MFMA -----------------------------------
__global__ __launch_bounds__(256) void k_mlp2(const __half* __restrict__ hid16,
                                              const __half* __restrict__ W2_16p,
                                              const float* __restrict__ b2,
                                              float* __restrict__ out, int n)
{
    int t = threadIdx.x, lane = t & 63;
    int rowbase = blockIdx.x * 64 + (t >> 6) * 16;
    int mr = rowbase + (lane & 15);
    if (mr >= n) mr = n - 1;
    int kg = (lane >> 4) * 8;
    f32x4 acc[8] = {};
#pragma unroll
    for (int ks = 0; ks < 8; ++ks) {
        half8 af = *(const half8*)(hid16 + ((size_t)mr << 8) + ks * 32 + kg);
#pragma unroll
        for (int ct = 0; ct < 8; ++ct) {
            half8 bf = *(const half8*)(W2_16p + (((ct << 4) + (lane & 15)) << 8)
                                              + ks * 32 + kg);
            acc[ct] = MFMA16(af, bf, acc[ct]);
        }
    }
#pragma unroll
    for (int ct = 0; ct < 8; ++ct) {
        int col = (ct << 4) + (lane & 15);
        if (col >= 119) continue;
        float bb = b2[col];
#pragma unroll
        for (int r = 0; r < 4; ++r) {
            int node = rowbase + ((lane >> 4) << 2) + r;
            if (node < n)
                out[(size_t)node * 119 + col] = acc[ct][r] + bb;
        }
    }
}

extern "C" void kernel_launch(void* const* d_in, const int* in_sizes, int n_in,
                              void* d_out, int out_size, void* d_ws, size_t ws_size,
                              hipStream_t stream)
{
    const float* x    = (const float*)d_in[0];
    const int*   ei   = (const int*)d_in[1];    // [2,E]
    const int*   ea   = (const int*)d_in[2];    // [E,2]
    const int*   midx = (const int*)d_in[3];    // [NM]
    const float* pa   = (const float*)d_in[4];  // scalar
    const float* Wen  = (const float*)d_in[5];  // [128,128]
    const float* emb1 = (const float*)d_in[6];  // [6,128]
    const float* emb2 = (const float*)d_in[7];  // [3,128]
    const float* W1   = (const float*)d_in[8];  // [256,128]
    const float* b1   = (const float*)d_in[9];  // [256]
    const float* W2   = (const float*)d_in[10]; // [119,256]
    const float* b2   = (const float*)d_in[11]; // [119]
    float* out = (float*)d_out;

    int n  = in_sizes[0] / 128;
    int E  = in_sizes[1] / 2;
    int nm = in_sizes[3];

    char* ws = (char*)d_ws;
    size_t HB = (size_t)n * 128 * 2;            // 12.8 MB (fp16 n x 128)
    __half* aggr16 = (__half*)ws;               // [0, HB)
    __half* h16    = (__half*)(ws + HB);        // [HB, 2HB)
    __half* hid16  = (__half*)(ws + 2 * HB);    // [2HB, 4HB)
    char* p = ws + 4 * HB;
    __half* Wen16  = (__half*)p;  p += 128 * 128 * 2;
    __half* W1_16  = (__half*)p;  p += 256 * 128 * 2;
    __half* W2_16p = (__half*)p;  p += 128 * 256 * 2;
    ull* cnt64  = (ull*)p;        p += (size_t)n * 8;
    int* cursor = (int*)p;        p += 256;
    int* off    = (int*)p;        p += (size_t)n * 4;
    int* cur    = (int*)p;        p += (size_t)n * 4;
    int* sorted = (int*)p;        p += (size_t)E * 4;   // total ~56 MB

    int nbEnc  = (n + 63) / 64;
    int nbHist = 512;

    hipMemsetAsync(cnt64, 0, (size_t)n * 8 + 256, stream);  // cnt64 + cursor

    k_wconv<<<128, 256, 0, stream>>>(Wen, W1, W2, Wen16, W1_16, W2_16p);
    k_pre  <<<nbEnc + nbHist, 256, 0, stream>>>(x, Wen16, pa, h16, ei, ea,
                                                cnt64, n, E, nbEnc, nbHist);
    k_mask <<<(nm * 64 + 255) / 256, 256, 0, stream>>>(midx, (unsigned int*)h16, nm);
    k_alloc<<<(n + 255) / 256, 256, 0, stream>>>(cnt64, off, cur, cursor, n);
    k_fill <<<(E + 255) / 256, 256, 0, stream>>>(ei, cur, sorted, E);
    k_agg  <<<(n + 3) / 4, 256, 0, stream>>>((const unsigned int*)h16, off, cnt64,
                                             sorted, emb1, emb2,
                                             (unsigned int*)aggr16, n);
    k_mlp1 <<<(n + 63) / 64, 256, 0, stream>>>(aggr16, W1_16, b1, hid16, n);
    k_mlp2 <<<(n + 63) / 64, 256, 0, stream>>>(hid16, W2_16p, b2, out, n);
}